// Round 3
// 362.737 us; speedup vs baseline: 1.6395x; 1.6395x over previous
//
#include <hip/hip_runtime.h>

#define IN_SIZE 256
#define N_NODES 1024
#define DEG 32
#define BATCH 16384
#define OUT_SIZE 16
#define COLS 8                        // batch columns per single-wave block
#define N_ROWS (IN_SIZE + N_NODES)    // 1280 activation rows (fp32 in LDS)

// RNE float -> bf16
__device__ __forceinline__ unsigned short f2bf_rne(float f) {
    const unsigned u = __float_as_uint(f);
    return (unsigned short)((u + 0x7FFFu + ((u >> 16) & 1u)) >> 16);
}

// butterfly add across lane bits {0,1,2}: masks 1 (quad_perm B1), 2 (quad_perm 4E),
// 7 (row_half_mirror = lane^7). XOR-butterfly over span{1,2,7} = full 8-lane sum
// in every lane, bitwise-identical across lanes. CTRL must be an ICE -> template.
template <int CTRL>
__device__ __forceinline__ float dpp_add(float v) {
    return v + __int_as_float(__builtin_amdgcn_mov_dpp(__float_as_int(v), CTRL, 0xF, 0xF, true));
}

// ---------------------------------------------------------------------------
// Runtime dtype detector (unchanged).
// ---------------------------------------------------------------------------
__global__ __launch_bounds__(64) void ne_detect(const void* __restrict__ xraw,
                                                int* __restrict__ flag) {
    const unsigned short* xb = (const unsigned short*)xraw;
    const int tid = threadIdx.x;
    int plausible = 0;
    for (int k = tid; k < 2048; k += 64) {
        const float v = __uint_as_float((unsigned)xb[2 * k] << 16);
        const float a = fabsf(v);
        plausible += (a == 0.0f) || (a > 1e-3f && a < 1e3f) ? 1 : 0;
    }
    for (int off = 32; off > 0; off >>= 1) plausible += __shfl_down(plausible, off);
    if (tid == 0) *flag = (plausible >= (2048 * 9) / 10) ? 1 : 0;
}

// ---------------------------------------------------------------------------
// Weights -> fp32, plus per-node hazard scalars:
//   h1[n] = sum w[n][k] where idx[n][k] == 256+n-1   (n>=1)
//   h2[n] = sum w[n][k] where idx[n][k] == 256+n-2   (n>=2)
//   h3[n] = sum w[n][k] where idx[n][k] == 256+n-3   (n>=3)
// These fold the stale-row (read-as-zero) corrections into 3 batch-independent
// scalars so the hot loop needs zero per-lane hazard compares.
// ---------------------------------------------------------------------------
__global__ __launch_bounds__(256) void ne_prep(const void* __restrict__ wraw,
                                               const int* __restrict__ idxs,
                                               float* __restrict__ wf,
                                               float4* __restrict__ hz,
                                               const int* __restrict__ flag) {
    const int isbf16 = *flag;                    // uniform
    const int tid = blockIdx.x * 256 + threadIdx.x;
    const int stride = gridDim.x * 256;
    const unsigned short* wb = (const unsigned short*)wraw;
    const float* wsrc = (const float*)wraw;
    for (int k = tid; k < N_NODES * DEG; k += stride)
        wf[k] = isbf16 ? __uint_as_float((unsigned)wb[k] << 16) : wsrc[k];
    for (int n = tid; n < N_NODES; n += stride) {
        float h1 = 0.0f, h2 = 0.0f, h3 = 0.0f;
        const int r1 = IN_SIZE + n - 1, r2 = IN_SIZE + n - 2, r3 = IN_SIZE + n - 3;
        for (int k = 0; k < DEG; ++k) {
            const int id = idxs[n * DEG + k];
            const float w = isbf16 ? __uint_as_float((unsigned)wb[n * DEG + k] << 16)
                                   : wsrc[n * DEG + k];
            if (n >= 1 && id == r1) h1 += w;
            if (n >= 2 && id == r2) h2 += w;
            if (n >= 3 && id == r3) h3 += w;
        }
        hz[n] = make_float4(h1, h2, h3, 0.0f);
    }
}

// ---------------------------------------------------------------------------
// fp32 LDS activations (40 KB -> 4 blocks/CU, 2 rounds). Per step i:
//   reduce node i+1 (4 FMA + 3 DPP, consumes gathers issued at step i-2)
//   issue gathers node i+3 (stale rows 256+i..256+i+2 read pre-zeroed 0.0)
//   finalize node i: z = accR + h1*t_{i-1} + h2*t_{i-2} + h3*t_{i-3}; tanh
//   write t; refill slot i&7 with node i+8 (idx/w/hz, L2-hot, ~250cy ahead)
// Critical recurrence: t_{i-1} -> 1 FMA -> tanh -> t_i. Everything else is
// off-path. Single wave => in-order DS => stale reads deterministically 0.
// ---------------------------------------------------------------------------
__global__ __launch_bounds__(64) void ne_forward(const void* __restrict__ xraw,
                                                 const float* __restrict__ wf,
                                                 const int* __restrict__ in_idxs,
                                                 const float4* __restrict__ hz,
                                                 void* __restrict__ outraw,
                                                 const int* __restrict__ flag) {
    __shared__ float act[N_ROWS * COLS];         // 40960 B
    const int lane = threadIdx.x;
    const int q = lane & 7;                      // fan-in group (ids q*4..q*4+3)
    const int c = lane >> 3;                     // batch column 0..7
    const int c0 = blockIdx.x * COLS;
    const int q4 = q * 4;
    const int isbf16 = *flag;                    // uniform
    float* outf = (float*)outraw;
    unsigned short* outb = (unsigned short*)outraw;

    // ---- zero node rows so stale gathers read exactly 0.0 ----
    {
        float4* az = (float4*)(act + IN_SIZE * COLS);   // 2048 float4
#pragma unroll
        for (int t = 0; t < 32; ++t) az[t * 64 + lane] = make_float4(0.f, 0.f, 0.f, 0.f);
    }
    // ---- seed input rows 0..255 from raw x (fp32 in LDS) ----
    {
        const int b = c;
        if (isbf16) {
            const unsigned short* xb =
                (const unsigned short*)xraw + (size_t)(c0 + b) * IN_SIZE + q * 32;
#pragma unroll
            for (int t = 0; t < 4; ++t) {
                const uint4 v = *(const uint4*)(xb + t * 8);
                const int k0 = q * 32 + t * 8;
                act[(k0 + 0) * COLS + b] = __uint_as_float(v.x << 16);
                act[(k0 + 1) * COLS + b] = __uint_as_float(v.x & 0xFFFF0000u);
                act[(k0 + 2) * COLS + b] = __uint_as_float(v.y << 16);
                act[(k0 + 3) * COLS + b] = __uint_as_float(v.y & 0xFFFF0000u);
                act[(k0 + 4) * COLS + b] = __uint_as_float(v.z << 16);
                act[(k0 + 5) * COLS + b] = __uint_as_float(v.z & 0xFFFF0000u);
                act[(k0 + 6) * COLS + b] = __uint_as_float(v.w << 16);
                act[(k0 + 7) * COLS + b] = __uint_as_float(v.w & 0xFFFF0000u);
            }
        } else {
            const float* xs = (const float*)xraw + (size_t)(c0 + b) * IN_SIZE + q * 32;
#pragma unroll
            for (int t = 0; t < 8; ++t) {
                const float4 v = *(const float4*)(xs + t * 4);
                const int k0 = q * 32 + t * 4;
                act[(k0 + 0) * COLS + b] = v.x;
                act[(k0 + 1) * COLS + b] = v.y;
                act[(k0 + 2) * COLS + b] = v.z;
                act[(k0 + 3) * COLS + b] = v.w;
            }
        }
    }
    // single wave: in-order DS pipeline -> no barrier anywhere

    // ---- 8-slot rotation: slot k holds node (k mod 8)-congruent, 8 ahead ----
    int4 sid[8]; float4 swt[8]; float4 shz[8];
#pragma unroll
    for (int k = 0; k < 8; ++k) {
        sid[k] = *(const int4*)(in_idxs + k * DEG + q4);
        swt[k] = *(const float4*)(wf + k * DEG + q4);
        shz[k] = hz[k];
    }

    // ---- prologue: gathers n0->A, n1->B; reduce n0; gathers n2->A ----
    float gA0, gA1, gA2, gA3, gB0, gB1, gB2, gB3;
    { const int4 g = sid[0];
      gA0 = act[g.x * COLS + c]; gA1 = act[g.y * COLS + c];
      gA2 = act[g.z * COLS + c]; gA3 = act[g.w * COLS + c]; }
    { const int4 g = sid[1];
      gB0 = act[g.x * COLS + c]; gB1 = act[g.y * COLS + c];
      gB2 = act[g.z * COLS + c]; gB3 = act[g.w * COLS + c]; }
    float accA, accB;
    {
        const float4 wv = swt[0];
        float a = gA0 * wv.x; a = fmaf(gA1, wv.y, a);
        a = fmaf(gA2, wv.z, a); a = fmaf(gA3, wv.w, a);
        a = dpp_add<0xB1>(a); a = dpp_add<0x4E>(a); a = dpp_add<0x141>(a);
        accA = a;
    }
    { const int4 g = sid[2];
      gA0 = act[g.x * COLS + c]; gA1 = act[g.y * COLS + c];
      gA2 = act[g.z * COLS + c]; gA3 = act[g.w * COLS + c]; }

    float tp = 0.0f, tpp = 0.0f, tppp = 0.0f;

#define STEPM(i, K, S0, S1, S2, S3, ACCc, ACCn)                                        \
    {                                                                                  \
        /* reduce node i+1 (weights slot (K+1)&7; gathers issued 2 steps ago) */       \
        const float4 wv = swt[((K) + 1) & 7];                                          \
        float a = S0 * wv.x; a = fmaf(S1, wv.y, a);                                    \
        a = fmaf(S2, wv.z, a); a = fmaf(S3, wv.w, a);                                  \
        a = dpp_add<0xB1>(a); a = dpp_add<0x4E>(a); a = dpp_add<0x141>(a);             \
        ACCn = a;                                                                      \
        /* issue gathers node i+3 (before write(i): stale rows covered by h1..h3) */   \
        { const int4 g = sid[((K) + 3) & 7];                                           \
          S0 = act[g.x * COLS + c]; S1 = act[g.y * COLS + c];                          \
          S2 = act[g.z * COLS + c]; S3 = act[g.w * COLS + c]; }                        \
        /* finalize node i: critical chain = 1 fma (h.x*tp) + tanh */                  \
        const float4 h = shz[(K)];                                                     \
        float z = fmaf(h.z, tppp, ACCc);                                               \
        z = fmaf(h.y, tpp, z);                                                         \
        z = fmaf(h.x, tp, z);                                                          \
        const float s = __expf(-2.0f * fabsf(z));                                      \
        const float r = __builtin_amdgcn_rcpf(1.0f + s);                               \
        const float t = copysignf(fmaf(-s, r, r), z);                                  \
        if (q == 0) {                                                                  \
            act[(IN_SIZE + (i)) * COLS + c] = t;                                       \
            if ((i) >= N_NODES - OUT_SIZE) {                                           \
                const size_t o = (size_t)((i) - (N_NODES - OUT_SIZE)) * BATCH + c0 + c;\
                if (isbf16) outb[o] = f2bf_rne(t); else outf[o] = t;                   \
            }                                                                          \
        }                                                                              \
        /* refill slot K with node i+8 (clamped; L2-hot, ~5 steps of flight) */        \
        { const int np = ((i) + 8 < N_NODES) ? (i) + 8 : N_NODES - 1;                  \
          sid[(K)] = *(const int4*)(in_idxs + (size_t)np * DEG + q4);                  \
          swt[(K)] = *(const float4*)(wf + (size_t)np * DEG + q4);                     \
          shz[(K)] = hz[np]; }                                                         \
        tppp = tpp; tpp = tp; tp = t;                                                  \
    }

#pragma unroll 1
    for (int ii = 0; ii < N_NODES; ii += 8) {
        STEPM(ii + 0, 0, gB0, gB1, gB2, gB3, accA, accB)
        STEPM(ii + 1, 1, gA0, gA1, gA2, gA3, accB, accA)
        STEPM(ii + 2, 2, gB0, gB1, gB2, gB3, accA, accB)
        STEPM(ii + 3, 3, gA0, gA1, gA2, gA3, accB, accA)
        STEPM(ii + 4, 4, gB0, gB1, gB2, gB3, accA, accB)
        STEPM(ii + 5, 5, gA0, gA1, gA2, gA3, accB, accA)
        STEPM(ii + 6, 6, gB0, gB1, gB2, gB3, accA, accB)
        STEPM(ii + 7, 7, gA0, gA1, gA2, gA3, accB, accA)
    }
#undef STEPM
}

extern "C" void kernel_launch(void* const* d_in, const int* in_sizes, int n_in,
                              void* d_out, int out_size, void* d_ws, size_t ws_size,
                              hipStream_t stream) {
    const void* x   = d_in[0];                   // [BATCH][IN_SIZE]
    const void* w   = d_in[1];                   // [N_NODES][DEG]
    const int* idxs = (const int*)d_in[2];       // [N_NODES][DEG]

    float* wf   = (float*)d_ws;                                         // 128 KB
    float4* hz  = (float4*)((char*)d_ws + (size_t)N_NODES * DEG * 4);   // 16 KB
    int* flag   = (int*)((char*)d_ws + ((ws_size - 16) & ~(size_t)15));

    ne_detect<<<1, 64, 0, stream>>>(x, flag);
    ne_prep<<<32, 256, 0, stream>>>(w, idxs, wf, hz, flag);

    // 2048 single-wave blocks, 40 KB LDS -> 4 blocks/CU, 2 rounds, no barriers
    ne_forward<<<dim3(BATCH / COLS), dim3(64), 0, stream>>>(x, wf, idxs, hz, d_out, flag);
}

// Round 4
// 296.801 us; speedup vs baseline: 2.0038x; 1.2222x over previous
//
#include <hip/hip_runtime.h>

#define IN_SIZE 256
#define N_NODES 1024
#define DEG 32
#define BATCH 16384
#define OUT_SIZE 16
#define COLS 8                        // batch columns per single-wave block
#define N_ROWS (IN_SIZE + N_NODES)    // 1280 activation rows (fp32 in LDS)

// RNE float -> bf16
__device__ __forceinline__ unsigned short f2bf_rne(float f) {
    const unsigned u = __float_as_uint(f);
    return (unsigned short)((u + 0x7FFFu + ((u >> 16) & 1u)) >> 16);
}

// butterfly add across lane bits {0,1,2}: masks 1 (quad_perm B1), 2 (quad_perm 4E),
// 7 (row_half_mirror = lane^7). XOR-butterfly over span{1,2,7} = full 8-lane sum
// in every lane, bitwise-identical across lanes.
template <int CTRL>
__device__ __forceinline__ float dpp_add(float v) {
    return v + __int_as_float(__builtin_amdgcn_mov_dpp(__float_as_int(v), CTRL, 0xF, 0xF, true));
}

// ---------------------------------------------------------------------------
// Runtime dtype detector (unchanged).
// ---------------------------------------------------------------------------
__global__ __launch_bounds__(64) void ne_detect(const void* __restrict__ xraw,
                                                int* __restrict__ flag) {
    const unsigned short* xb = (const unsigned short*)xraw;
    const int tid = threadIdx.x;
    int plausible = 0;
    for (int k = tid; k < 2048; k += 64) {
        const float v = __uint_as_float((unsigned)xb[2 * k] << 16);
        const float a = fabsf(v);
        plausible += (a == 0.0f) || (a > 1e-3f && a < 1e3f) ? 1 : 0;
    }
    for (int off = 32; off > 0; off >>= 1) plausible += __shfl_down(plausible, off);
    if (tid == 0) *flag = (plausible >= (2048 * 9) / 10) ? 1 : 0;
}

// ---------------------------------------------------------------------------
// Weights -> fp32, plus per-node hazard scalars REPLICATED x8 so the hot
// loop's refill is a per-lane (vector, vmcnt) load — a uniform-address load
// would become s_load (SMEM), whose only wait is lgkmcnt(0), draining the
// in-flight gather ds_reads every step (the round-3 stall).
//   h1[n] = sum w[n][k] where idx[n][k] == 256+n-1   (etc. h2, h3)
// ---------------------------------------------------------------------------
__global__ __launch_bounds__(256) void ne_prep(const void* __restrict__ wraw,
                                               const int* __restrict__ idxs,
                                               float* __restrict__ wf,
                                               float4* __restrict__ hzr,
                                               const int* __restrict__ flag) {
    const int isbf16 = *flag;                    // uniform
    const int tid = blockIdx.x * 256 + threadIdx.x;
    const int stride = gridDim.x * 256;
    const unsigned short* wb = (const unsigned short*)wraw;
    const float* wsrc = (const float*)wraw;
    for (int k = tid; k < N_NODES * DEG; k += stride)
        wf[k] = isbf16 ? __uint_as_float((unsigned)wb[k] << 16) : wsrc[k];
    for (int n = tid; n < N_NODES; n += stride) {
        float h1 = 0.0f, h2 = 0.0f, h3 = 0.0f;
        const int r1 = IN_SIZE + n - 1, r2 = IN_SIZE + n - 2, r3 = IN_SIZE + n - 3;
        for (int k = 0; k < DEG; ++k) {
            const int id = idxs[n * DEG + k];
            const float w = isbf16 ? __uint_as_float((unsigned)wb[n * DEG + k] << 16)
                                   : wsrc[n * DEG + k];
            if (n >= 1 && id == r1) h1 += w;
            if (n >= 2 && id == r2) h2 += w;
            if (n >= 3 && id == r3) h3 += w;
        }
        const float4 h = make_float4(h1, h2, h3, 0.0f);
#pragma unroll
        for (int r = 0; r < 8; ++r) hzr[n * 8 + r] = h;
    }
}

// ---------------------------------------------------------------------------
// fp32 LDS activations (40 KB -> 4 blocks/CU, 2 rounds). Per step i:
//   reduce node i+1 (4 FMA + 3 DPP, consumes gathers issued at step i-2)
//   issue gathers node i+3 (stale rows 256+i..256+i+2 read pre-zeroed 0.0)
//   finalize node i: z = accR + h1*t_{i-1} + h2*t_{i-2} + h3*t_{i-3}; tanh
//   write t; refill slot i&7 with node i+8 (ALL vector loads -> vmcnt only)
// Critical recurrence: t_{i-1} -> 1 FMA -> tanh -> t_i. Single wave =>
// in-order DS => stale reads deterministically 0, zero barriers.
// ---------------------------------------------------------------------------
__global__ __launch_bounds__(64) void ne_forward(const void* __restrict__ xraw,
                                                 const float* __restrict__ wf,
                                                 const int* __restrict__ in_idxs,
                                                 const float4* __restrict__ hzr,
                                                 void* __restrict__ outraw,
                                                 const int* __restrict__ flag) {
    __shared__ float act[N_ROWS * COLS];         // 40960 B
    const int lane = threadIdx.x;
    const int q = lane & 7;                      // fan-in group (ids q*4..q*4+3)
    const int c = lane >> 3;                     // batch column 0..7
    const int c0 = blockIdx.x * COLS;
    const int q4 = q * 4;
    const int isbf16 = *flag;                    // uniform
    float* outf = (float*)outraw;
    unsigned short* outb = (unsigned short*)outraw;

    // ---- zero node rows so stale gathers read exactly 0.0 ----
    {
        float4* az = (float4*)(act + IN_SIZE * COLS);   // 2048 float4
#pragma unroll
        for (int t = 0; t < 32; ++t) az[t * 64 + lane] = make_float4(0.f, 0.f, 0.f, 0.f);
    }
    // ---- seed input rows 0..255 from raw x (fp32 in LDS) ----
    {
        const int b = c;
        if (isbf16) {
            const unsigned short* xb =
                (const unsigned short*)xraw + (size_t)(c0 + b) * IN_SIZE + q * 32;
#pragma unroll
            for (int t = 0; t < 4; ++t) {
                const uint4 v = *(const uint4*)(xb + t * 8);
                const int k0 = q * 32 + t * 8;
                act[(k0 + 0) * COLS + b] = __uint_as_float(v.x << 16);
                act[(k0 + 1) * COLS + b] = __uint_as_float(v.x & 0xFFFF0000u);
                act[(k0 + 2) * COLS + b] = __uint_as_float(v.y << 16);
                act[(k0 + 3) * COLS + b] = __uint_as_float(v.y & 0xFFFF0000u);
                act[(k0 + 4) * COLS + b] = __uint_as_float(v.z << 16);
                act[(k0 + 5) * COLS + b] = __uint_as_float(v.z & 0xFFFF0000u);
                act[(k0 + 6) * COLS + b] = __uint_as_float(v.w << 16);
                act[(k0 + 7) * COLS + b] = __uint_as_float(v.w & 0xFFFF0000u);
            }
        } else {
            const float* xs = (const float*)xraw + (size_t)(c0 + b) * IN_SIZE + q * 32;
#pragma unroll
            for (int t = 0; t < 8; ++t) {
                const float4 v = *(const float4*)(xs + t * 4);
                const int k0 = q * 32 + t * 4;
                act[(k0 + 0) * COLS + b] = v.x;
                act[(k0 + 1) * COLS + b] = v.y;
                act[(k0 + 2) * COLS + b] = v.z;
                act[(k0 + 3) * COLS + b] = v.w;
            }
        }
    }
    // single wave: in-order DS pipeline -> no barrier anywhere

    // ---- 8-slot rotation: slot k holds node k, refilled 8 ahead ----
    int4 sid[8]; float4 swt[8]; float4 shz[8];
#pragma unroll
    for (int k = 0; k < 8; ++k) {
        sid[k] = *(const int4*)(in_idxs + k * DEG + q4);
        swt[k] = *(const float4*)(wf + k * DEG + q4);
        shz[k] = hzr[k * 8 + q];                 // per-lane addr -> vector load
    }

    // ---- prologue: gathers n0->A, n1->B; reduce n0; gathers n2->A ----
    float gA0, gA1, gA2, gA3, gB0, gB1, gB2, gB3;
    { const int4 g = sid[0];
      gA0 = act[g.x * COLS + c]; gA1 = act[g.y * COLS + c];
      gA2 = act[g.z * COLS + c]; gA3 = act[g.w * COLS + c]; }
    { const int4 g = sid[1];
      gB0 = act[g.x * COLS + c]; gB1 = act[g.y * COLS + c];
      gB2 = act[g.z * COLS + c]; gB3 = act[g.w * COLS + c]; }
    float accA, accB;
    {
        const float4 wv = swt[0];
        float a = gA0 * wv.x; a = fmaf(gA1, wv.y, a);
        a = fmaf(gA2, wv.z, a); a = fmaf(gA3, wv.w, a);
        a = dpp_add<0xB1>(a); a = dpp_add<0x4E>(a); a = dpp_add<0x141>(a);
        accA = a;
    }
    { const int4 g = sid[2];
      gA0 = act[g.x * COLS + c]; gA1 = act[g.y * COLS + c];
      gA2 = act[g.z * COLS + c]; gA3 = act[g.w * COLS + c]; }

    float tp = 0.0f, tpp = 0.0f, tppp = 0.0f;

// OUT: compile-time 0/1 (output store). CLAMP: refill index clamping.
#define STEPM(i, K, S0, S1, S2, S3, ACCc, ACCn, OUT, CLAMP)                            \
    {                                                                                  \
        /* reduce node i+1 (weights slot (K+1)&7; gathers issued 2 steps ago) */       \
        const float4 wv = swt[((K) + 1) & 7];                                          \
        float a = S0 * wv.x; a = fmaf(S1, wv.y, a);                                    \
        a = fmaf(S2, wv.z, a); a = fmaf(S3, wv.w, a);                                  \
        a = dpp_add<0xB1>(a); a = dpp_add<0x4E>(a); a = dpp_add<0x141>(a);             \
        ACCn = a;                                                                      \
        /* issue gathers node i+3 (before write(i): stale rows covered by h1..h3) */   \
        { const int4 g = sid[((K) + 3) & 7];                                           \
          S0 = act[g.x * COLS + c]; S1 = act[g.y * COLS + c];                          \
          S2 = act[g.z * COLS + c]; S3 = act[g.w * COLS + c]; }                        \
        /* finalize node i: critical chain = 1 fma (h.x*tp) + tanh */                  \
        const float4 h = shz[(K)];                                                     \
        float z = fmaf(h.z, tppp, ACCc);                                               \
        z = fmaf(h.y, tpp, z);                                                         \
        z = fmaf(h.x, tp, z);                                                          \
        const float s = __expf(-2.0f * fabsf(z));                                      \
        const float r = __builtin_amdgcn_rcpf(1.0f + s);                               \
        const float t = copysignf(fmaf(-s, r, r), z);                                  \
        if (q == 0) {                                                                  \
            act[(IN_SIZE + (i)) * COLS + c] = t;                                       \
            if (OUT) {                                                                 \
                const size_t o = (size_t)((i) - (N_NODES - OUT_SIZE)) * BATCH + c0 + c;\
                if (isbf16) outb[o] = f2bf_rne(t); else outf[o] = t;                   \
            }                                                                          \
        }                                                                              \
        /* refill slot K with node i+8 (all vector loads, vmcnt-tracked) */            \
        { const int np = (CLAMP) ? (((i) + 8 < N_NODES) ? (i) + 8 : N_NODES - 1)       \
                                 : (i) + 8;                                            \
          sid[(K)] = *(const int4*)(in_idxs + (size_t)np * DEG + q4);                  \
          swt[(K)] = *(const float4*)(wf + (size_t)np * DEG + q4);                     \
          shz[(K)] = hzr[np * 8 + q]; }                                                \
        tppp = tpp; tpp = tp; tp = t;                                                  \
    }

    // main loop: nodes 0..1007 — no output check, no refill clamp (i+8 <= 1015)
#pragma unroll 1
    for (int ii = 0; ii < N_NODES - OUT_SIZE; ii += 8) {
        STEPM(ii + 0, 0, gB0, gB1, gB2, gB3, accA, accB, 0, 0)
        STEPM(ii + 1, 1, gA0, gA1, gA2, gA3, accB, accA, 0, 0)
        STEPM(ii + 2, 2, gB0, gB1, gB2, gB3, accA, accB, 0, 0)
        STEPM(ii + 3, 3, gA0, gA1, gA2, gA3, accB, accA, 0, 0)
        STEPM(ii + 4, 4, gB0, gB1, gB2, gB3, accA, accB, 0, 0)
        STEPM(ii + 5, 5, gA0, gA1, gA2, gA3, accB, accA, 0, 0)
        STEPM(ii + 6, 6, gB0, gB1, gB2, gB3, accA, accB, 0, 0)
        STEPM(ii + 7, 7, gA0, gA1, gA2, gA3, accB, accA, 0, 0)
    }
    // epilogue: nodes 1008..1023 — every node is an output node
    {
        const int ii = N_NODES - OUT_SIZE;       // 1008
        STEPM(ii + 0, 0, gB0, gB1, gB2, gB3, accA, accB, 1, 1)
        STEPM(ii + 1, 1, gA0, gA1, gA2, gA3, accB, accA, 1, 1)
        STEPM(ii + 2, 2, gB0, gB1, gB2, gB3, accA, accB, 1, 1)
        STEPM(ii + 3, 3, gA0, gA1, gA2, gA3, accB, accA, 1, 1)
        STEPM(ii + 4, 4, gB0, gB1, gB2, gB3, accA, accB, 1, 1)
        STEPM(ii + 5, 5, gA0, gA1, gA2, gA3, accB, accA, 1, 1)
        STEPM(ii + 6, 6, gB0, gB1, gB2, gB3, accA, accB, 1, 1)
        STEPM(ii + 7, 7, gA0, gA1, gA2, gA3, accB, accA, 1, 1)
        STEPM(ii + 8, 0, gB0, gB1, gB2, gB3, accA, accB, 1, 1)
        STEPM(ii + 9, 1, gA0, gA1, gA2, gA3, accB, accA, 1, 1)
        STEPM(ii + 10, 2, gB0, gB1, gB2, gB3, accA, accB, 1, 1)
        STEPM(ii + 11, 3, gA0, gA1, gA2, gA3, accB, accA, 1, 1)
        STEPM(ii + 12, 4, gB0, gB1, gB2, gB3, accA, accB, 1, 1)
        STEPM(ii + 13, 5, gA0, gA1, gA2, gA3, accB, accA, 1, 1)
        STEPM(ii + 14, 6, gB0, gB1, gB2, gB3, accA, accB, 1, 1)
        STEPM(ii + 15, 7, gA0, gA1, gA2, gA3, accB, accA, 1, 1)
    }
#undef STEPM
}

extern "C" void kernel_launch(void* const* d_in, const int* in_sizes, int n_in,
                              void* d_out, int out_size, void* d_ws, size_t ws_size,
                              hipStream_t stream) {
    const void* x   = d_in[0];                   // [BATCH][IN_SIZE]
    const void* w   = d_in[1];                   // [N_NODES][DEG]
    const int* idxs = (const int*)d_in[2];       // [N_NODES][DEG]

    float* wf   = (float*)d_ws;                                          // 128 KB
    float4* hzr = (float4*)((char*)d_ws + (size_t)N_NODES * DEG * 4);    // 128 KB
    int* flag   = (int*)((char*)d_ws + ((ws_size - 16) & ~(size_t)15));

    ne_detect<<<1, 64, 0, stream>>>(x, flag);
    ne_prep<<<32, 256, 0, stream>>>(w, idxs, wf, hzr, flag);

    // 2048 single-wave blocks, 40 KB LDS -> 4 blocks/CU, 2 rounds, no barriers
    ne_forward<<<dim3(BATCH / COLS), dim3(64), 0, stream>>>(x, wf, idxs, hzr, d_out, flag);
}